// Round 1
// baseline (260.988 us; speedup 1.0000x reference)
//
#include <hip/hip_runtime.h>
#include <math.h>

// HOG layer: input x (1,3,4096,4096) fp32 -> feat (511,511,36) fp32.
// Only pixels at (8i+7, 8j+7) are sampled (512x512 grid), so we compute
// gradients only there. Fused single kernel: 16x16 output cells per block,
// 17x17 9-bin histograms staged in LDS, then 4-neighbor gather + L2 norm.

#define IMG 4096
#define CSTRIDE (4096 * 4096)
#define NCELL 512          // sample grid
#define NOUT 511           // output cells per dim
#define TS 16              // output tile per block
#define HT 17              // hist tile per block (TS+1)

__device__ __forceinline__ float load_s(const float* __restrict__ x, int y, int xx) {
    // channel-sum, same order as jnp sum over axis 1: (c0 + c1) + c2
    size_t idx = (size_t)y * IMG + xx;
    return (x[idx] + x[idx + CSTRIDE]) + x[idx + 2 * (size_t)CSTRIDE];
}

__device__ __forceinline__ void hist9(const float* __restrict__ x, int gr, int gc,
                                      float* __restrict__ out /* 9 floats (LDS) */) {
    const int y = 8 * gr + 7;
    const int xx = 8 * gc + 7;
    // y-1 = 8gr+6 >= 6 and x-1 >= 6 always valid; only the +1 side can pad.
    const float s_up = load_s(x, y - 1, xx);
    const float s_dn = (y + 1 < IMG) ? load_s(x, y + 1, xx) : 0.0f;
    const float s_lf = load_s(x, y, xx - 1);
    const float s_rt = (xx + 1 < IMG) ? load_s(x, y, xx + 1) : 0.0f;

    const float g_v = s_dn - s_up;
    const float g_h = s_rt - s_lf;

    const float mag = sqrtf(g_v * g_v + g_h * g_h + 1e-6f);
    const float ang = fabsf(atanf(g_h / (g_v + 1e-9f)) * 57.29577951308232f); // deg, [0,90]

    const float jf = floorf(ang / 20.0f - 0.5f);        // in {-1..4}
    const float vj = mag * ((20.0f * (jf + 1.5f) - ang) / 20.0f);
    const float vj1 = mag - vj;
    const int ji = (int)jf;
    const int i0 = (ji + 9) % 9;
    const int i1 = (i0 + 1) % 9;

#pragma unroll
    for (int b = 0; b < 9; ++b) out[b] = 0.0f;
    out[i0] = vj;
    out[i1] = vj1;   // i0 != i1 always (differ by 1 mod 9)
}

__global__ __launch_bounds__(256) void hog_kernel(const float* __restrict__ x,
                                                  float* __restrict__ out) {
    __shared__ float hist[HT * HT * 9];  // 2601 floats = 10.4 KB

    const int bi = blockIdx.y;
    const int bj = blockIdx.x;
    const int tid = threadIdx.x;  // 0..255

    // Phase 1: fill 17x17 histogram tile
    for (int e = tid; e < HT * HT; e += 256) {
        const int r = e / HT;
        const int c = e % HT;
        int gr = bi * TS + r; if (gr > NCELL - 1) gr = NCELL - 1;  // clamp (unused dup)
        int gc = bj * TS + c; if (gc > NCELL - 1) gc = NCELL - 1;
        hist9(x, gr, gc, &hist[e * 9]);
    }
    __syncthreads();

    // Phase 2: one thread per output cell
    const int ty = tid >> 4;
    const int tx = tid & 15;
    const int oi = bi * TS + ty;
    const int oj = bj * TS + tx;
    if (oi >= NOUT || oj >= NOUT) return;

    const float* h00 = &hist[((ty    ) * HT + tx    ) * 9];
    const float* h01 = &hist[((ty    ) * HT + tx + 1) * 9];
    const float* h10 = &hist[((ty + 1) * HT + tx    ) * 9];
    const float* h11 = &hist[((ty + 1) * HT + tx + 1) * 9];

    float v[36];
#pragma unroll
    for (int b = 0; b < 9; ++b) {
        v[b]      = h00[b];
        v[9 + b]  = h01[b];
        v[18 + b] = h10[b];
        v[27 + b] = h11[b];
    }
    float ss = 0.0f;
#pragma unroll
    for (int c = 0; c < 36; ++c) ss += v[c] * v[c];
    const float inv = 1.0f / (sqrtf(ss) + 1e-9f);

    float* o = out + ((size_t)oi * NOUT + oj) * 36;
#pragma unroll
    for (int c = 0; c < 36; ++c) o[c] = v[c] * inv;
}

extern "C" void kernel_launch(void* const* d_in, const int* in_sizes, int n_in,
                              void* d_out, int out_size, void* d_ws, size_t ws_size,
                              hipStream_t stream) {
    (void)in_sizes; (void)n_in; (void)d_ws; (void)ws_size; (void)out_size;
    const float* x = (const float*)d_in[0];
    float* out = (float*)d_out;

    dim3 grid((NOUT + TS - 1) / TS, (NOUT + TS - 1) / TS);  // 32 x 32
    dim3 block(256);
    hipLaunchKernelGGL(hog_kernel, grid, block, 0, stream, x, out);
}

// Round 2
// 255.640 us; speedup vs baseline: 1.0209x; 1.0209x over previous
//
#include <hip/hip_runtime.h>
#include <math.h>

// HOG layer: x (1,3,4096,4096) fp32 -> feat (511,511,36) fp32.
// Only pixels at (8i+7, 8j+7) are sampled. Per 16x16-cell block:
//   Phase A: coalesced float4 staging of the 51 needed image rows
//            (y = 8g+{6,7,8}) x 136 cols, channel-summed, into LDS.
//   Phase B: 17x17 cell histograms (9 bins) from LDS samples.
//   Phase C: 4 lanes per output cell (one quadrant each), shfl reduce
//            for L2 norm, 36B/lane contiguous stores.

#define IMG 4096
#define CSTRIDE (4096 * 4096)
#define NOUT 511
#define TS 16
#define HT 17          // cells per block dim (TS+1)
#define NROWS 51       // 3*HT image rows staged
#define NQ 34          // float4 quads per staged row
#define RS 136         // floats per staged row (NQ*4)

__global__ __launch_bounds__(256) void hog_kernel(const float* __restrict__ x,
                                                  float* __restrict__ out) {
    __shared__ float raw[NROWS * RS];     // 27744 B channel-summed pixels
    __shared__ float hist[HT * HT * 9];   // 10404 B cell histograms

    const int bi = blockIdx.y, bj = blockIdx.x, tid = threadIdx.x;
    const int col0 = 128 * bj + 4;        // 16B-aligned staging base column

    // ---- Phase A: coalesced load + channel sum -> LDS -------------------
    // row rr = 3r+dt  <->  image row y = 8*(16bi+r) + 6 + dt
    for (int t = tid; t < NROWS * NQ; t += 256) {
        const int rr = t / NQ;
        const int q  = t - rr * NQ;
        const int r  = rr / 3;
        const int dt = rr - 3 * r;
        const int y  = 128 * bi + 8 * r + 6 + dt;
        const int gc = col0 + 4 * q;
        float4 v = make_float4(0.f, 0.f, 0.f, 0.f);
        if (y < IMG && gc + 3 < IMG) {           // OOB -> zeros == jnp.pad
            const size_t base = (size_t)y * IMG + gc;
            const float4 a = *(const float4*)(x + base);
            const float4 b = *(const float4*)(x + base + (size_t)CSTRIDE);
            const float4 c = *(const float4*)(x + base + 2 * (size_t)CSTRIDE);
            v.x = (a.x + b.x) + c.x;
            v.y = (a.y + b.y) + c.y;
            v.z = (a.z + b.z) + c.z;
            v.w = (a.w + b.w) + c.w;
        }
        *(float4*)&raw[rr * RS + 4 * q] = v;     // 16B-aligned ds_write_b128
    }
    __syncthreads();

    // ---- Phase B: 17x17 cell histograms --------------------------------
    // cell (r,k): sample pixel (8*(16bi+r)+7, 8*(16bj+k)+7)
    //   up  = raw[3r  ][8k+3]   dn = raw[3r+2][8k+3]
    //   lf  = raw[3r+1][8k+2]   rt = raw[3r+1][8k+4]
    for (int cell = tid; cell < HT * HT; cell += 256) {
        const int r = cell / HT;
        const int k = cell - r * HT;
        const float s_up = raw[(3 * r    ) * RS + 8 * k + 3];
        const float s_lf = raw[(3 * r + 1) * RS + 8 * k + 2];
        const float s_rt = raw[(3 * r + 1) * RS + 8 * k + 4];
        const float s_dn = raw[(3 * r + 2) * RS + 8 * k + 3];

        const float g_v = s_dn - s_up;
        const float g_h = s_rt - s_lf;
        const float mag = sqrtf(g_v * g_v + g_h * g_h + 1e-6f);
        const float ang = fabsf(atanf(g_h / (g_v + 1e-9f)) * 57.29577951308232f);
        const float jf  = floorf(ang * 0.05f - 0.5f);       // in {-1..4}
        const float vj  = mag * ((20.0f * (jf + 1.5f) - ang) * 0.05f);
        const float vj1 = mag - vj;
        int i0 = (int)jf; if (i0 < 0) i0 += 9;              // mod 9, range-based
        const int i1 = (i0 == 8) ? 0 : i0 + 1;

        float* h = &hist[cell * 9];
#pragma unroll
        for (int b = 0; b < 9; ++b)
            h[b] = (b == i0) ? vj : ((b == i1) ? vj1 : 0.0f);
    }
    __syncthreads();

    // ---- Phase C: 4 lanes per output cell, quadrant each ---------------
    const int p  = tid & 3;          // quadrant: h00,h01,h10,h11
    const int c0 = tid >> 2;         // 0..63: cell within group
    for (int it = 0; it < 4; ++it) {
        const int cell = it * 64 + c0;       // 0..255 in 16x16 tile
        const int ty = cell >> 4;
        const int tx = cell & 15;
        const int hr = ty + (p >> 1);
        const int hc = tx + (p & 1);
        const float* h = &hist[(hr * HT + hc) * 9];
        float v[9];
        float ss = 0.f;
#pragma unroll
        for (int b = 0; b < 9; ++b) { v[b] = h[b]; ss += v[b] * v[b]; }
        ss += __shfl_xor(ss, 1);             // reduce across the 4 quadrant lanes
        ss += __shfl_xor(ss, 2);
        const int oi = 16 * bi + ty;
        const int oj = 16 * bj + tx;
        if (oi < NOUT && oj < NOUT) {
            const float inv = 1.0f / (sqrtf(ss) + 1e-9f);
            float* o = out + ((size_t)oi * NOUT + oj) * 36 + p * 9;
#pragma unroll
            for (int b = 0; b < 9; ++b) o[b] = v[b] * inv;
        }
    }
}

extern "C" void kernel_launch(void* const* d_in, const int* in_sizes, int n_in,
                              void* d_out, int out_size, void* d_ws, size_t ws_size,
                              hipStream_t stream) {
    (void)in_sizes; (void)n_in; (void)d_ws; (void)ws_size; (void)out_size;
    const float* x = (const float*)d_in[0];
    float* out = (float*)d_out;
    dim3 grid(32, 32);   // 16x16 output cells per block, 511x511 total
    dim3 block(256);
    hipLaunchKernelGGL(hog_kernel, grid, block, 0, stream, x, out);
}